// Round 6
// baseline (46.467 us; speedup 1.0000x reference)
//
#include <hip/hip_runtime.h>
#include <stdint.h>

#define NG 256
#define HW (512*512)
#define NCELL 1024          // 32x32 cells
#define CAP 384             // bucket capacity per cell (Poisson(256), max ~330)
#define SPILL_CAP 4096
#define PXB 4096            // pixels per bin-block
#define TWO_PI_F 6.283185307179586f
#define L2E 1.4426950408889634f
#define INV2PI_D 0.15915494309189535

static __device__ __forceinline__ float clampf(float x, float lo, float hi) {
    return fminf(fmaxf(x, lo), hi);
}

// ---------- per-gabor constants (f64 -> correctly-rounded f32) ----------
static __device__ __forceinline__ void compute_consts(
    int n,
    const float* __restrict__ u, const float* __restrict__ v,
    const float* __restrict__ theta, const float* __restrict__ rel_sigma,
    const float* __restrict__ rel_freq, const float* __restrict__ gamma,
    const float* __restrict__ psi, const float* __restrict__ amplitude,
    float4& A, float4& B, float4& C, float4& D)
{
    const float uc = clampf(u[n], -1.f, 1.f);
    const float vc = clampf(v[n], -1.f, 1.f);
    const float th = clampf(theta[n], -2.f, 2.f) * TWO_PI_F;
    const float sg = clampf(rel_sigma[n], 1e-5f, 5.f);
    const float gm = clampf(gamma[n], 1e-5f, 5.f);
    const float cr = (float)::cos((double)th);
    const float sr = (float)::sin((double)th);
    const float i2s = 1.0f / (2.0f * sg * sg);
    const float i2g = 1.0f / (2.0f * gm * gm);
    const float E  = (float)::exp((double)rel_freq[n]);
    const float fq = TWO_PI_F / E;          // f32 division, mirrors np
    A = make_float4(uc, vc, cr, sr);
    B = make_float4(-(i2s * L2E), -(i2g * L2E), fq, 0.f);  // ready for exp2
    float ac[3], as[3];
    #pragma unroll
    for (int c = 0; c < 3; ++c) {
        const float ph = clampf(psi[n*3 + c], -1.f, 1.f) * TWO_PI_F;
        const float a  = clampf(amplitude[n*3 + c], 0.f, 1.f);
        ac[c] = a * (float)::cos((double)ph);
        as[c] = a * (float)::sin((double)ph);
    }
    C = make_float4(ac[0], ac[1], ac[2], 0.f);
    D = make_float4(as[0], as[1], as[2], 0.f);
}

// ---------- 1-pixel accumulate (spill + fallback paths) ----------
static __device__ __forceinline__ void accum_list(
    const float4* __restrict__ base, int ngab,
    float gx, float gy, float& a0, float& a1, float& a2)
{
    const float c1f = 0.15915494309189535f;
    const float c2f = (float)(INV2PI_D - (double)0.15915494309189535f);
    for (int j = 0; j < ngab; ++j) {
        const float4 k0 = base[j];
        const float4 k1 = base[NG + j];
        const float dx = gx - k0.x;
        const float dy = gy - k0.y;
        float xr, yr;
        {
            #pragma clang fp contract(off)
            xr = dx * k0.z + dy * k0.w;
            yr = dy * k0.z - dx * k0.w;
        }
        const float e2 = fmaf(yr * yr, k1.y, xr * xr * k1.x);
        if (e2 > -20.0f) {
            const float g = __builtin_amdgcn_exp2f(e2);
            float fx;
            {
                #pragma clang fp contract(off)
                fx = k1.z * xr;
            }
            const float nn = __builtin_rintf(fx * c1f);
            float t = __builtin_fmaf(fx, c1f, -nn);
            t = __builtin_fmaf(fx, c2f, t);
            const float s = __builtin_amdgcn_sinf(t);
            const float c = __builtin_amdgcn_cosf(t);
            const float4 k2 = base[2*NG + j];
            const float4 k3 = base[3*NG + j];
            const float gc = g * c, gs = g * s;
            a0 = fmaf(gc, k2.x, fmaf(-gs, k3.x, a0));
            a1 = fmaf(gc, k2.y, fmaf(-gs, k3.y, a1));
            a2 = fmaf(gc, k2.z, fmaf(-gs, k3.z, a2));
        }
    }
}

// ---------- kernel A: binning (blocks 0..63) + consts (block 64) ----------
__global__ __launch_bounds__(256) void gabor_bin_consts(
    const float* __restrict__ grid_x, const float* __restrict__ grid_y,
    const float* __restrict__ u, const float* __restrict__ v,
    const float* __restrict__ theta, const float* __restrict__ rel_sigma,
    const float* __restrict__ rel_freq, const float* __restrict__ gamma,
    const float* __restrict__ psi, const float* __restrict__ amplitude,
    float4* __restrict__ consts, int* __restrict__ counts,
    int* __restrict__ bucket, float2* __restrict__ bxy,
    int* __restrict__ spill, int* __restrict__ spilln)
{
    const int tid = threadIdx.x;
    if (blockIdx.x == 64) {    // consts block, runs concurrently with binning
        float4 A, B, C, D;
        compute_consts(tid, u, v, theta, rel_sigma, rel_freq, gamma, psi,
                       amplitude, A, B, C, D);
        consts[tid] = A; consts[NG+tid] = B;
        consts[2*NG+tid] = C; consts[3*NG+tid] = D;
        return;
    }
    __shared__ int hist[NCELL];
    __shared__ int base[NCELL];
    #pragma unroll
    for (int i = 0; i < NCELL/256; ++i) hist[i*256 + tid] = 0;
    __syncthreads();

    uint32_t rec[PXB/256];
    const int p0 = blockIdx.x * PXB;
    #pragma unroll
    for (int i = 0; i < PXB/256; ++i) {
        const int p = p0 + i*256 + tid;
        const float x = grid_x[p], y = grid_y[p];
        int ix = (int)(x * 32.0f); ix = min(max(ix, 0), 31);
        int iy = (int)(y * 32.0f); iy = min(max(iy, 0), 31);
        const int cell = iy*32 + ix;
        const int lr = atomicAdd(&hist[cell], 1);       // LDS atomic: cheap
        rec[i] = ((uint32_t)cell << 13) | (uint32_t)lr;
    }
    __syncthreads();
    #pragma unroll
    for (int i = 0; i < NCELL/256; ++i) {
        const int c = i*256 + tid;
        const int h = hist[c];
        base[c] = (h > 0) ? atomicAdd(&counts[c], h) : 0;  // 64/address max
    }
    __syncthreads();
    #pragma unroll
    for (int i = 0; i < PXB/256; ++i) {
        const int p = p0 + i*256 + tid;
        const int cell = (int)(rec[i] >> 13);
        const int g = base[cell] + (int)(rec[i] & 0x1FFFu);
        if (g < CAP) {
            bucket[cell*CAP + g] = p;
            bxy[cell*CAP + g] = make_float2(grid_x[p], grid_y[p]); // L1/L2 hot
        } else {
            const int t2 = atomicAdd(spilln, 1);
            if (t2 < SPILL_CAP) spill[t2] = p;
        }
    }
}

// ---------- kernel B: render, inline cull, 2 px/thread ----------
__global__ __launch_bounds__(128) void gabor_render(
    const float4* __restrict__ consts, const int* __restrict__ counts,
    const int* __restrict__ bucket, const float2* __restrict__ bxy,
    const int* __restrict__ spill, const int* __restrict__ spilln,
    const float* __restrict__ grid_x, const float* __restrict__ grid_y,
    float* __restrict__ out)
{
    __shared__ float4 cs[4 * NG];
    __shared__ int s_wb[2];
    const int cell = blockIdx.x;
    const int tid = threadIdx.x;
    const float cxc = ((cell & 31) + 0.5f) * 0.03125f;
    const float cyc = ((cell >> 5) + 0.5f) * 0.03125f;

    // --- inline cull: 2 gabors/thread, order-preserving LDS compaction ---
    int total = 0;
    #pragma unroll
    for (int r = 0; r < 2; ++r) {
        const int g = r*128 + tid;
        const float4 A = consts[g];
        const float4 B = consts[NG + g];
        const float4 C = consts[2*NG + g];
        const float4 D = consts[3*NG + g];
        const float dx = cxc - A.x, dy = cyc - A.y;
        const float xrc = dx * A.z + dy * A.w;
        const float yrc = dy * A.z - dx * A.w;
        const float R = 0.0222f;            // cell half-diagonal + slack
        const float xl = fmaxf(fabsf(xrc) - R, 0.f);
        const float yl = fmaxf(fabsf(yrc) - R, 0.f);
        const float e2max = xl*xl*B.x + yl*yl*B.y;   // conservative bound
        const bool nz = (C.x != 0.f) | (C.y != 0.f) | (C.z != 0.f) |
                        (D.x != 0.f) | (D.y != 0.f) | (D.z != 0.f);
        const bool act = (e2max > -20.0f) && nz;
        const unsigned long long m = __ballot(act);
        const int lane = tid & 63, w = tid >> 6;
        if (lane == 0) s_wb[w] = __popcll(m);
        __syncthreads();
        const int pos = total + (w ? s_wb[0] : 0)
                      + __popcll(m & ((1ull << lane) - 1ull));
        if (act) { cs[pos] = A; cs[NG+pos] = B; cs[2*NG+pos] = C; cs[3*NG+pos] = D; }
        total += s_wb[0] + s_wb[1];
        __syncthreads();
    }
    const int ng = total;

    // --- pixel loop: 2 px/thread, preamble amortized across 128 px/wave ---
    const float c1f = 0.15915494309189535f;
    const float c2f = (float)(INV2PI_D - (double)0.15915494309189535f);
    const int cnt = min(counts[cell], CAP);
    const int sb = cell * CAP;
    for (int b0 = 0; b0 < cnt; b0 += 256) {
        const int i0 = b0 + 2*tid;
        if (i0 >= cnt) continue;            // tail waves self-disable
        const int i1 = i0 + 1;
        const bool v1 = i1 < cnt;
        const float2 xy0 = bxy[sb + i0];
        const float2 xy1 = v1 ? bxy[sb + i1] : xy0;
        float p00 = 0.f, p01 = 0.f, p02 = 0.f;
        float p10 = 0.f, p11 = 0.f, p12 = 0.f;
        for (int j = 0; j < ng; ++j) {
            const float4 k0 = cs[j];
            const float4 k1 = cs[NG + j];
            const float dx0 = xy0.x - k0.x, dy0 = xy0.y - k0.y;
            const float dx1 = xy1.x - k0.x, dy1 = xy1.y - k0.y;
            float xr0, yr0, xr1, yr1;
            {
                // phase-critical: match np's separately-rounded mul/add
                #pragma clang fp contract(off)
                xr0 = dx0 * k0.z + dy0 * k0.w;
                yr0 = dy0 * k0.z - dx0 * k0.w;
                xr1 = dx1 * k0.z + dy1 * k0.w;
                yr1 = dy1 * k0.z - dx1 * k0.w;
            }
            const float e20 = fmaf(yr0*yr0, k1.y, xr0*xr0 * k1.x);
            const float e21 = fmaf(yr1*yr1, k1.y, xr1*xr1 * k1.x);
            if (e20 > -20.0f || e21 > -20.0f) {
                // dead pixel is harmless: exp2(huge negative) -> 0
                const float g0 = __builtin_amdgcn_exp2f(e20);
                const float g1 = __builtin_amdgcn_exp2f(e21);
                float fx0, fx1;
                {
                    #pragma clang fp contract(off)
                    fx0 = k1.z * xr0;        // phase-critical rounding
                    fx1 = k1.z * xr1;
                }
                const float n0 = __builtin_rintf(fx0 * c1f);
                const float n1 = __builtin_rintf(fx1 * c1f);
                float t0 = __builtin_fmaf(fx0, c1f, -n0);
                float t1 = __builtin_fmaf(fx1, c1f, -n1);
                t0 = __builtin_fmaf(fx0, c2f, t0);
                t1 = __builtin_fmaf(fx1, c2f, t1);
                const float s0 = __builtin_amdgcn_sinf(t0);
                const float c0 = __builtin_amdgcn_cosf(t0);
                const float s1 = __builtin_amdgcn_sinf(t1);
                const float c1 = __builtin_amdgcn_cosf(t1);
                const float4 k2 = cs[2*NG + j];
                const float4 k3 = cs[3*NG + j];
                const float gc0 = g0*c0, gs0 = g0*s0;
                const float gc1 = g1*c1, gs1 = g1*s1;
                p00 = fmaf(gc0, k2.x, fmaf(-gs0, k3.x, p00));
                p01 = fmaf(gc0, k2.y, fmaf(-gs0, k3.y, p01));
                p02 = fmaf(gc0, k2.z, fmaf(-gs0, k3.z, p02));
                p10 = fmaf(gc1, k2.x, fmaf(-gs1, k3.x, p10));
                p11 = fmaf(gc1, k2.y, fmaf(-gs1, k3.y, p11));
                p12 = fmaf(gc1, k2.z, fmaf(-gs1, k3.z, p12));
            }
        }
        const int p0 = bucket[sb + i0];
        out[p0]        = clampf(p00, -1.f, 1.f);
        out[HW + p0]   = clampf(p01, -1.f, 1.f);
        out[2*HW + p0] = clampf(p02, -1.f, 1.f);
        if (v1) {
            const int p1 = bucket[sb + i1];
            out[p1]        = clampf(p10, -1.f, 1.f);
            out[HW + p1]   = clampf(p11, -1.f, 1.f);
            out[2*HW + p1] = clampf(p12, -1.f, 1.f);
        }
    }

    // spill pixels (normally zero) handled by block 0 with full gabor list
    if (cell == 0) {
        const int sc = min(*spilln, SPILL_CAP);
        for (int i = tid; i < sc; i += 128) {
            const int p = spill[i];
            const float gx = grid_x[p], gy = grid_y[p];
            float a0 = 0.f, a1 = 0.f, a2 = 0.f;
            accum_list(consts, NG, gx, gy, a0, a1, a2);
            out[p]        = clampf(a0, -1.f, 1.f);
            out[HW + p]   = clampf(a1, -1.f, 1.f);
            out[2*HW + p] = clampf(a2, -1.f, 1.f);
        }
    }
}

// ---------- fallback paths (ws too small) ----------
__global__ __launch_bounds__(256) void gabor_consts_kernel(
    const float* __restrict__ u, const float* __restrict__ v,
    const float* __restrict__ theta, const float* __restrict__ rel_sigma,
    const float* __restrict__ rel_freq, const float* __restrict__ gamma,
    const float* __restrict__ psi, const float* __restrict__ amplitude,
    float4* __restrict__ ws)
{
    const int n = threadIdx.x;
    float4 A, B, C, D;
    compute_consts(n, u, v, theta, rel_sigma, rel_freq, gamma, psi, amplitude,
                   A, B, C, D);
    ws[n] = A; ws[NG + n] = B; ws[2*NG + n] = C; ws[3*NG + n] = D;
}

__global__ __launch_bounds__(256) void gabor_fwd_ws(
    const float4* __restrict__ ws,
    const float* __restrict__ grid_x, const float* __restrict__ grid_y,
    float* __restrict__ out)
{
    __shared__ float4 cs[4 * NG];
    const int tid = threadIdx.x;
    cs[tid]        = ws[tid];
    cs[tid + NG]   = ws[tid + NG];
    cs[tid + 2*NG] = ws[tid + 2*NG];
    cs[tid + 3*NG] = ws[tid + 3*NG];
    __syncthreads();
    const int p = blockIdx.x * 256 + tid;
    const float gx = grid_x[p], gy = grid_y[p];
    float a0 = 0.f, a1 = 0.f, a2 = 0.f;
    accum_list(cs, NG, gx, gy, a0, a1, a2);
    out[p]        = clampf(a0, -1.f, 1.f);
    out[HW + p]   = clampf(a1, -1.f, 1.f);
    out[2*HW + p] = clampf(a2, -1.f, 1.f);
}

__global__ __launch_bounds__(256) void gabor_fwd_fused(
    const float* __restrict__ grid_x, const float* __restrict__ grid_y,
    const float* __restrict__ u, const float* __restrict__ v,
    const float* __restrict__ theta, const float* __restrict__ rel_sigma,
    const float* __restrict__ rel_freq, const float* __restrict__ gamma,
    const float* __restrict__ psi, const float* __restrict__ amplitude,
    float* __restrict__ out)
{
    __shared__ float4 cs[4 * NG];
    const int tid = threadIdx.x;
    {
        float4 A, B, C, D;
        compute_consts(tid, u, v, theta, rel_sigma, rel_freq, gamma, psi,
                       amplitude, A, B, C, D);
        cs[tid] = A; cs[tid + NG] = B; cs[tid + 2*NG] = C; cs[tid + 3*NG] = D;
    }
    __syncthreads();
    const int p = blockIdx.x * 256 + tid;
    const float gx = grid_x[p], gy = grid_y[p];
    float a0 = 0.f, a1 = 0.f, a2 = 0.f;
    accum_list(cs, NG, gx, gy, a0, a1, a2);
    out[p]        = clampf(a0, -1.f, 1.f);
    out[HW + p]   = clampf(a1, -1.f, 1.f);
    out[2*HW + p] = clampf(a2, -1.f, 1.f);
}

extern "C" void kernel_launch(void* const* d_in, const int* in_sizes, int n_in,
                              void* d_out, int out_size, void* d_ws, size_t ws_size,
                              hipStream_t stream) {
    const float* grid_x    = (const float*)d_in[0];
    const float* grid_y    = (const float*)d_in[1];
    const float* u         = (const float*)d_in[2];
    const float* v         = (const float*)d_in[3];
    const float* theta     = (const float*)d_in[4];
    const float* rel_sigma = (const float*)d_in[5];
    const float* rel_freq  = (const float*)d_in[6];
    const float* gamma     = (const float*)d_in[7];
    const float* psi       = (const float*)d_in[8];
    const float* amplitude = (const float*)d_in[9];
    float* out = (float*)d_out;

    // ws layout (256B-aligned)
    const size_t OFF_CONSTS = 0;            // 16384
    const size_t OFF_COUNTS = 16384;        // 4096
    const size_t OFF_SPN    = 20480;        // 256
    const size_t OFF_SPILL  = 20736;        // 16384
    const size_t OFF_BUCKET = 37120;        // 1572864
    const size_t OFF_BXY    = 1609984;      // 3145728
    const size_t NEED       = 4755712;

    char* w = (char*)d_ws;

    if (ws_size >= NEED) {
        float4* consts = (float4*)(w + OFF_CONSTS);
        int*    counts = (int*)(w + OFF_COUNTS);
        int*    spn    = (int*)(w + OFF_SPN);
        int*    spill  = (int*)(w + OFF_SPILL);
        int*    bucket = (int*)(w + OFF_BUCKET);
        float2* bxy    = (float2*)(w + OFF_BXY);

        // zero counts + spilln (graph-capturable memset node)
        hipMemsetAsync(w + OFF_COUNTS, 0, 4096 + 256, stream);
        gabor_bin_consts<<<65, 256, 0, stream>>>(
            grid_x, grid_y, u, v, theta, rel_sigma, rel_freq, gamma,
            psi, amplitude, consts, counts, bucket, bxy, spill, spn);
        gabor_render<<<NCELL, 128, 0, stream>>>(
            consts, counts, bucket, bxy, spill, spn, grid_x, grid_y, out);
    } else if (ws_size >= 4u * NG * sizeof(float4)) {
        float4* ws = (float4*)d_ws;
        gabor_consts_kernel<<<1, NG, 0, stream>>>(
            u, v, theta, rel_sigma, rel_freq, gamma, psi, amplitude, ws);
        gabor_fwd_ws<<<HW / 256, 256, 0, stream>>>(ws, grid_x, grid_y, out);
    } else {
        gabor_fwd_fused<<<HW / 256, 256, 0, stream>>>(
            grid_x, grid_y, u, v, theta, rel_sigma, rel_freq, gamma,
            psi, amplitude, out);
    }
}

// Round 7
// 38.961 us; speedup vs baseline: 1.1926x; 1.1926x over previous
//
#include <hip/hip_runtime.h>
#include <stdint.h>

#define NG 256
#define HW (512*512)
#define NCELL 1024          // 32x32 cells
#define CAP 384             // bucket capacity per cell (Poisson(256), max ~330)
#define SPILL_CAP 4096
#define PXB 4096            // pixels per bin-block
#define TWO_PI_F 6.283185307179586f
#define L2E 1.4426950408889634f
#define INV2PI_D 0.15915494309189535

static __device__ __forceinline__ float clampf(float x, float lo, float hi) {
    return fminf(fmaxf(x, lo), hi);
}

// ---------- per-gabor constants (f64 -> correctly-rounded f32) ----------
static __device__ __forceinline__ void compute_consts(
    int n,
    const float* __restrict__ u, const float* __restrict__ v,
    const float* __restrict__ theta, const float* __restrict__ rel_sigma,
    const float* __restrict__ rel_freq, const float* __restrict__ gamma,
    const float* __restrict__ psi, const float* __restrict__ amplitude,
    float4& A, float4& B, float4& C, float4& D)
{
    const float uc = clampf(u[n], -1.f, 1.f);
    const float vc = clampf(v[n], -1.f, 1.f);
    const float th = clampf(theta[n], -2.f, 2.f) * TWO_PI_F;
    const float sg = clampf(rel_sigma[n], 1e-5f, 5.f);
    const float gm = clampf(gamma[n], 1e-5f, 5.f);
    const float cr = (float)::cos((double)th);
    const float sr = (float)::sin((double)th);
    const float i2s = 1.0f / (2.0f * sg * sg);
    const float i2g = 1.0f / (2.0f * gm * gm);
    const float E  = (float)::exp((double)rel_freq[n]);
    const float fq = TWO_PI_F / E;          // f32 division, mirrors np
    A = make_float4(uc, vc, cr, sr);
    B = make_float4(-(i2s * L2E), -(i2g * L2E), fq, 0.f);  // ready for exp2
    float ac[3], as[3];
    #pragma unroll
    for (int c = 0; c < 3; ++c) {
        const float ph = clampf(psi[n*3 + c], -1.f, 1.f) * TWO_PI_F;
        const float a  = clampf(amplitude[n*3 + c], 0.f, 1.f);
        ac[c] = a * (float)::cos((double)ph);
        as[c] = a * (float)::sin((double)ph);
    }
    C = make_float4(ac[0], ac[1], ac[2], 0.f);
    D = make_float4(as[0], as[1], as[2], 0.f);
}

// ---------- 1-pixel accumulate (spill + fallback paths) ----------
static __device__ __forceinline__ void accum_list(
    const float4* __restrict__ base, int ngab,
    float gx, float gy, float& a0, float& a1, float& a2)
{
    const float c1f = 0.15915494309189535f;
    const float c2f = (float)(INV2PI_D - (double)0.15915494309189535f);
    for (int j = 0; j < ngab; ++j) {
        const float4 k0 = base[j];
        const float4 k1 = base[NG + j];
        const float dx = gx - k0.x;
        const float dy = gy - k0.y;
        float xr, yr;
        {
            #pragma clang fp contract(off)
            xr = dx * k0.z + dy * k0.w;
            yr = dy * k0.z - dx * k0.w;
        }
        const float e2 = fmaf(yr * yr, k1.y, xr * xr * k1.x);
        if (e2 > -20.0f) {
            const float g = __builtin_amdgcn_exp2f(e2);
            float fx;
            {
                #pragma clang fp contract(off)
                fx = k1.z * xr;
            }
            const float nn = __builtin_rintf(fx * c1f);
            float t = __builtin_fmaf(fx, c1f, -nn);
            t = __builtin_fmaf(fx, c2f, t);
            const float s = __builtin_amdgcn_sinf(t);
            const float c = __builtin_amdgcn_cosf(t);
            const float4 k2 = base[2*NG + j];
            const float4 k3 = base[3*NG + j];
            const float gc = g * c, gs = g * s;
            a0 = fmaf(gc, k2.x, fmaf(-gs, k3.x, a0));
            a1 = fmaf(gc, k2.y, fmaf(-gs, k3.y, a1));
            a2 = fmaf(gc, k2.z, fmaf(-gs, k3.z, a2));
        }
    }
}

// ---------- kernel A: binning (blocks 0..63) + consts (block 64) ----------
__global__ __launch_bounds__(256) void gabor_bin_consts(
    const float* __restrict__ grid_x, const float* __restrict__ grid_y,
    const float* __restrict__ u, const float* __restrict__ v,
    const float* __restrict__ theta, const float* __restrict__ rel_sigma,
    const float* __restrict__ rel_freq, const float* __restrict__ gamma,
    const float* __restrict__ psi, const float* __restrict__ amplitude,
    float4* __restrict__ consts, int* __restrict__ counts,
    int* __restrict__ bucket, float2* __restrict__ bxy,
    int* __restrict__ spill, int* __restrict__ spilln)
{
    const int tid = threadIdx.x;
    if (blockIdx.x == 64) {    // consts block, runs concurrently with binning
        float4 A, B, C, D;
        compute_consts(tid, u, v, theta, rel_sigma, rel_freq, gamma, psi,
                       amplitude, A, B, C, D);
        consts[tid] = A; consts[NG+tid] = B;
        consts[2*NG+tid] = C; consts[3*NG+tid] = D;
        return;
    }
    __shared__ int hist[NCELL];
    __shared__ int base[NCELL];
    #pragma unroll
    for (int i = 0; i < NCELL/256; ++i) hist[i*256 + tid] = 0;
    __syncthreads();

    uint32_t rec[PXB/256];
    const int p0 = blockIdx.x * PXB;
    #pragma unroll
    for (int i = 0; i < PXB/256; ++i) {
        const int p = p0 + i*256 + tid;
        const float x = grid_x[p], y = grid_y[p];
        int ix = (int)(x * 32.0f); ix = min(max(ix, 0), 31);
        int iy = (int)(y * 32.0f); iy = min(max(iy, 0), 31);
        const int cell = iy*32 + ix;
        const int lr = atomicAdd(&hist[cell], 1);       // LDS atomic: cheap
        rec[i] = ((uint32_t)cell << 13) | (uint32_t)lr;
    }
    __syncthreads();
    #pragma unroll
    for (int i = 0; i < NCELL/256; ++i) {
        const int c = i*256 + tid;
        const int h = hist[c];
        base[c] = (h > 0) ? atomicAdd(&counts[c], h) : 0;  // 64/address max
    }
    __syncthreads();
    #pragma unroll
    for (int i = 0; i < PXB/256; ++i) {
        const int p = p0 + i*256 + tid;
        const int cell = (int)(rec[i] >> 13);
        const int g = base[cell] + (int)(rec[i] & 0x1FFFu);
        if (g < CAP) {
            bucket[cell*CAP + g] = p;
            bxy[cell*CAP + g] = make_float2(grid_x[p], grid_y[p]); // L1-hot
        } else {
            const int t2 = atomicAdd(spilln, 1);
            if (t2 < SPILL_CAP) spill[t2] = p;
        }
    }
}

// ---------- kernel B: render, inline cull, 1 px/thread, 2 blocks/cell ----------
__global__ __launch_bounds__(128) void gabor_render(
    const float4* __restrict__ consts, const int* __restrict__ counts,
    const int* __restrict__ bucket, const float2* __restrict__ bxy,
    const int* __restrict__ spill, const int* __restrict__ spilln,
    const float* __restrict__ grid_x, const float* __restrict__ grid_y,
    float* __restrict__ out)
{
    __shared__ float4 cs[4 * NG];
    __shared__ int s_wb[2];
    const int cell = blockIdx.x >> 1, par = blockIdx.x & 1;
    const int tid = threadIdx.x;
    const float cxc = ((cell & 31) + 0.5f) * 0.03125f;
    const float cyc = ((cell >> 5) + 0.5f) * 0.03125f;

    // --- inline cull: 2 gabors/thread, order-preserving LDS compaction ---
    int total = 0;
    #pragma unroll
    for (int r = 0; r < 2; ++r) {
        const int g = r*128 + tid;
        const float4 A = consts[g];
        const float4 B = consts[NG + g];
        const float4 C = consts[2*NG + g];
        const float4 D = consts[3*NG + g];
        const float dx = cxc - A.x, dy = cyc - A.y;
        const float xrc = dx * A.z + dy * A.w;
        const float yrc = dy * A.z - dx * A.w;
        const float R = 0.0222f;            // cell half-diagonal + slack
        const float xl = fmaxf(fabsf(xrc) - R, 0.f);
        const float yl = fmaxf(fabsf(yrc) - R, 0.f);
        const float e2max = xl*xl*B.x + yl*yl*B.y;   // conservative bound
        const bool nz = (C.x != 0.f) | (C.y != 0.f) | (C.z != 0.f) |
                        (D.x != 0.f) | (D.y != 0.f) | (D.z != 0.f);
        const bool act = (e2max > -20.0f) && nz;
        const unsigned long long m = __ballot(act);
        const int lane = tid & 63, w = tid >> 6;
        if (lane == 0) s_wb[w] = __popcll(m);
        __syncthreads();
        const int pos = total + (w ? s_wb[0] : 0)
                      + __popcll(m & ((1ull << lane) - 1ull));
        if (act) { cs[pos] = A; cs[NG+pos] = B; cs[2*NG+pos] = C; cs[3*NG+pos] = D; }
        total += s_wb[0] + s_wb[1];
        __syncthreads();
    }
    const int ng = total;

    // --- pixel loop: 1 px/thread, 64 same-cell px per wave ---
    const float c1f = 0.15915494309189535f;
    const float c2f = (float)(INV2PI_D - (double)0.15915494309189535f);
    const int cnt = min(counts[cell], CAP);
    const int sb = cell * CAP;
    for (int i = par*128 + tid; i < cnt; i += 256) {
        const float2 xy = bxy[sb + i];
        float a0 = 0.f, a1 = 0.f, a2 = 0.f;
        #pragma unroll 2
        for (int j = 0; j < ng; ++j) {
            const float4 k0 = cs[j];
            const float4 k1 = cs[NG + j];
            const float dx = xy.x - k0.x;
            const float dy = xy.y - k0.y;
            float xr, yr;
            {
                // phase-critical: match np's separately-rounded mul/add
                #pragma clang fp contract(off)
                xr = dx * k0.z + dy * k0.w;
                yr = dy * k0.z - dx * k0.w;
            }
            const float e2 = fmaf(yr * yr, k1.y, xr * xr * k1.x);
            if (e2 > -20.0f) {
                const float g = __builtin_amdgcn_exp2f(e2);
                float fx;
                {
                    #pragma clang fp contract(off)
                    fx = k1.z * xr;          // phase-critical rounding
                }
                const float nn = __builtin_rintf(fx * c1f);
                float t = __builtin_fmaf(fx, c1f, -nn);
                t = __builtin_fmaf(fx, c2f, t);
                const float s = __builtin_amdgcn_sinf(t);
                const float c = __builtin_amdgcn_cosf(t);
                const float4 k2 = cs[2*NG + j];
                const float4 k3 = cs[3*NG + j];
                const float gc = g * c, gs = g * s;
                a0 = fmaf(gc, k2.x, fmaf(-gs, k3.x, a0));
                a1 = fmaf(gc, k2.y, fmaf(-gs, k3.y, a1));
                a2 = fmaf(gc, k2.z, fmaf(-gs, k3.z, a2));
            }
        }
        const int p = bucket[sb + i];
        out[p]        = clampf(a0, -1.f, 1.f);
        out[HW + p]   = clampf(a1, -1.f, 1.f);
        out[2*HW + p] = clampf(a2, -1.f, 1.f);
    }

    // spill pixels (normally zero) handled by block 0 with full gabor list
    if (blockIdx.x == 0) {
        const int sc = min(*spilln, SPILL_CAP);
        for (int i = tid; i < sc; i += 128) {
            const int p = spill[i];
            const float gx = grid_x[p], gy = grid_y[p];
            float a0 = 0.f, a1 = 0.f, a2 = 0.f;
            accum_list(consts, NG, gx, gy, a0, a1, a2);
            out[p]        = clampf(a0, -1.f, 1.f);
            out[HW + p]   = clampf(a1, -1.f, 1.f);
            out[2*HW + p] = clampf(a2, -1.f, 1.f);
        }
    }
}

// ---------- fallback paths (ws too small) ----------
__global__ __launch_bounds__(256) void gabor_consts_kernel(
    const float* __restrict__ u, const float* __restrict__ v,
    const float* __restrict__ theta, const float* __restrict__ rel_sigma,
    const float* __restrict__ rel_freq, const float* __restrict__ gamma,
    const float* __restrict__ psi, const float* __restrict__ amplitude,
    float4* __restrict__ ws)
{
    const int n = threadIdx.x;
    float4 A, B, C, D;
    compute_consts(n, u, v, theta, rel_sigma, rel_freq, gamma, psi, amplitude,
                   A, B, C, D);
    ws[n] = A; ws[NG + n] = B; ws[2*NG + n] = C; ws[3*NG + n] = D;
}

__global__ __launch_bounds__(256) void gabor_fwd_ws(
    const float4* __restrict__ ws,
    const float* __restrict__ grid_x, const float* __restrict__ grid_y,
    float* __restrict__ out)
{
    __shared__ float4 cs[4 * NG];
    const int tid = threadIdx.x;
    cs[tid]        = ws[tid];
    cs[tid + NG]   = ws[tid + NG];
    cs[tid + 2*NG] = ws[tid + 2*NG];
    cs[tid + 3*NG] = ws[tid + 3*NG];
    __syncthreads();
    const int p = blockIdx.x * 256 + tid;
    const float gx = grid_x[p], gy = grid_y[p];
    float a0 = 0.f, a1 = 0.f, a2 = 0.f;
    accum_list(cs, NG, gx, gy, a0, a1, a2);
    out[p]        = clampf(a0, -1.f, 1.f);
    out[HW + p]   = clampf(a1, -1.f, 1.f);
    out[2*HW + p] = clampf(a2, -1.f, 1.f);
}

__global__ __launch_bounds__(256) void gabor_fwd_fused(
    const float* __restrict__ grid_x, const float* __restrict__ grid_y,
    const float* __restrict__ u, const float* __restrict__ v,
    const float* __restrict__ theta, const float* __restrict__ rel_sigma,
    const float* __restrict__ rel_freq, const float* __restrict__ gamma,
    const float* __restrict__ psi, const float* __restrict__ amplitude,
    float* __restrict__ out)
{
    __shared__ float4 cs[4 * NG];
    const int tid = threadIdx.x;
    {
        float4 A, B, C, D;
        compute_consts(tid, u, v, theta, rel_sigma, rel_freq, gamma, psi,
                       amplitude, A, B, C, D);
        cs[tid] = A; cs[tid + NG] = B; cs[tid + 2*NG] = C; cs[tid + 3*NG] = D;
    }
    __syncthreads();
    const int p = blockIdx.x * 256 + tid;
    const float gx = grid_x[p], gy = grid_y[p];
    float a0 = 0.f, a1 = 0.f, a2 = 0.f;
    accum_list(cs, NG, gx, gy, a0, a1, a2);
    out[p]        = clampf(a0, -1.f, 1.f);
    out[HW + p]   = clampf(a1, -1.f, 1.f);
    out[2*HW + p] = clampf(a2, -1.f, 1.f);
}

extern "C" void kernel_launch(void* const* d_in, const int* in_sizes, int n_in,
                              void* d_out, int out_size, void* d_ws, size_t ws_size,
                              hipStream_t stream) {
    const float* grid_x    = (const float*)d_in[0];
    const float* grid_y    = (const float*)d_in[1];
    const float* u         = (const float*)d_in[2];
    const float* v         = (const float*)d_in[3];
    const float* theta     = (const float*)d_in[4];
    const float* rel_sigma = (const float*)d_in[5];
    const float* rel_freq  = (const float*)d_in[6];
    const float* gamma     = (const float*)d_in[7];
    const float* psi       = (const float*)d_in[8];
    const float* amplitude = (const float*)d_in[9];
    float* out = (float*)d_out;

    // ws layout (256B-aligned)
    const size_t OFF_CONSTS = 0;            // 16384
    const size_t OFF_COUNTS = 16384;        // 4096
    const size_t OFF_SPN    = 20480;        // 256
    const size_t OFF_SPILL  = 20736;        // 16384
    const size_t OFF_BUCKET = 37120;        // 1572864
    const size_t OFF_BXY    = 1609984;      // 3145728
    const size_t NEED       = 4755712;

    char* w = (char*)d_ws;

    if (ws_size >= NEED) {
        float4* consts = (float4*)(w + OFF_CONSTS);
        int*    counts = (int*)(w + OFF_COUNTS);
        int*    spn    = (int*)(w + OFF_SPN);
        int*    spill  = (int*)(w + OFF_SPILL);
        int*    bucket = (int*)(w + OFF_BUCKET);
        float2* bxy    = (float2*)(w + OFF_BXY);

        // zero counts + spilln (graph-capturable memset node)
        hipMemsetAsync(w + OFF_COUNTS, 0, 4096 + 256, stream);
        gabor_bin_consts<<<65, 256, 0, stream>>>(
            grid_x, grid_y, u, v, theta, rel_sigma, rel_freq, gamma,
            psi, amplitude, consts, counts, bucket, bxy, spill, spn);
        gabor_render<<<2*NCELL, 128, 0, stream>>>(
            consts, counts, bucket, bxy, spill, spn, grid_x, grid_y, out);
    } else if (ws_size >= 4u * NG * sizeof(float4)) {
        float4* ws = (float4*)d_ws;
        gabor_consts_kernel<<<1, NG, 0, stream>>>(
            u, v, theta, rel_sigma, rel_freq, gamma, psi, amplitude, ws);
        gabor_fwd_ws<<<HW / 256, 256, 0, stream>>>(ws, grid_x, grid_y, out);
    } else {
        gabor_fwd_fused<<<HW / 256, 256, 0, stream>>>(
            grid_x, grid_y, u, v, theta, rel_sigma, rel_freq, gamma,
            psi, amplitude, out);
    }
}

// Round 8
// 38.091 us; speedup vs baseline: 1.2199x; 1.0228x over previous
//
#include <hip/hip_runtime.h>
#include <stdint.h>

#define NG 256
#define HW (512*512)
#define NCELL 1024          // 32x32 cells
#define CAP 384             // bucket capacity per cell (Poisson(256), max ~330)
#define SPILL_CAP 4096
#define NBIN 256            // bin blocks
#define PXB (HW/NBIN)       // 1024 pixels per bin-block
#define TWO_PI_F 6.283185307179586f
#define L2E 1.4426950408889634f
#define INV2PI_D 0.15915494309189535

static __device__ __forceinline__ float clampf(float x, float lo, float hi) {
    return fminf(fmaxf(x, lo), hi);
}

// ---------- per-gabor constants (f64 -> correctly-rounded f32) ----------
static __device__ __forceinline__ void compute_consts(
    int n,
    const float* __restrict__ u, const float* __restrict__ v,
    const float* __restrict__ theta, const float* __restrict__ rel_sigma,
    const float* __restrict__ rel_freq, const float* __restrict__ gamma,
    const float* __restrict__ psi, const float* __restrict__ amplitude,
    float4& A, float4& B, float4& C, float4& D)
{
    const float uc = clampf(u[n], -1.f, 1.f);
    const float vc = clampf(v[n], -1.f, 1.f);
    const float th = clampf(theta[n], -2.f, 2.f) * TWO_PI_F;
    const float sg = clampf(rel_sigma[n], 1e-5f, 5.f);
    const float gm = clampf(gamma[n], 1e-5f, 5.f);
    const float cr = (float)::cos((double)th);
    const float sr = (float)::sin((double)th);
    const float i2s = 1.0f / (2.0f * sg * sg);
    const float i2g = 1.0f / (2.0f * gm * gm);
    const float E  = (float)::exp((double)rel_freq[n]);
    const float fq = TWO_PI_F / E;          // f32 division, mirrors np
    A = make_float4(uc, vc, cr, sr);
    B = make_float4(-(i2s * L2E), -(i2g * L2E), fq, 0.f);  // ready for exp2
    float ac[3], as[3];
    #pragma unroll
    for (int c = 0; c < 3; ++c) {
        const float ph = clampf(psi[n*3 + c], -1.f, 1.f) * TWO_PI_F;
        const float a  = clampf(amplitude[n*3 + c], 0.f, 1.f);
        ac[c] = a * (float)::cos((double)ph);
        as[c] = a * (float)::sin((double)ph);
    }
    C = make_float4(ac[0], ac[1], ac[2], 0.f);
    D = make_float4(as[0], as[1], as[2], 0.f);
}

// ---------- 1-pixel accumulate (spill + fallback paths) ----------
static __device__ __forceinline__ void accum_list(
    const float4* __restrict__ base, int ngab,
    float gx, float gy, float& a0, float& a1, float& a2)
{
    const float c1f = 0.15915494309189535f;
    const float c2f = (float)(INV2PI_D - (double)0.15915494309189535f);
    for (int j = 0; j < ngab; ++j) {
        const float4 k0 = base[j];
        const float4 k1 = base[NG + j];
        const float dx = gx - k0.x;
        const float dy = gy - k0.y;
        float xr, yr;
        {
            #pragma clang fp contract(off)
            xr = dx * k0.z + dy * k0.w;
            yr = dy * k0.z - dx * k0.w;
        }
        const float e2 = fmaf(yr * yr, k1.y, xr * xr * k1.x);
        if (e2 > -20.0f) {
            const float g = __builtin_amdgcn_exp2f(e2);
            float fx;
            {
                #pragma clang fp contract(off)
                fx = k1.z * xr;
            }
            const float nn = __builtin_rintf(fx * c1f);
            float t = __builtin_fmaf(fx, c1f, -nn);
            t = __builtin_fmaf(fx, c2f, t);
            const float s = __builtin_amdgcn_sinf(t);
            const float c = __builtin_amdgcn_cosf(t);
            const float4 k2 = base[2*NG + j];
            const float4 k3 = base[3*NG + j];
            const float gc = g * c, gs = g * s;
            a0 = fmaf(gc, k2.x, fmaf(-gs, k3.x, a0));
            a1 = fmaf(gc, k2.y, fmaf(-gs, k3.y, a1));
            a2 = fmaf(gc, k2.z, fmaf(-gs, k3.z, a2));
        }
    }
}

// ---------- kernel A: binning (blocks 0..255) + consts (block 256) ----------
__global__ __launch_bounds__(256) void gabor_bin_consts(
    const float* __restrict__ grid_x, const float* __restrict__ grid_y,
    const float* __restrict__ u, const float* __restrict__ v,
    const float* __restrict__ theta, const float* __restrict__ rel_sigma,
    const float* __restrict__ rel_freq, const float* __restrict__ gamma,
    const float* __restrict__ psi, const float* __restrict__ amplitude,
    float4* __restrict__ consts, int* __restrict__ counts,
    float4* __restrict__ bpx,
    int* __restrict__ spill, int* __restrict__ spilln)
{
    const int tid = threadIdx.x;
    if (blockIdx.x == NBIN) {  // consts block, runs concurrently with binning
        float4 A, B, C, D;
        compute_consts(tid, u, v, theta, rel_sigma, rel_freq, gamma, psi,
                       amplitude, A, B, C, D);
        consts[tid] = A; consts[NG+tid] = B;
        consts[2*NG+tid] = C; consts[3*NG+tid] = D;
        return;
    }
    __shared__ int hist[NCELL];
    __shared__ int base[NCELL];
    #pragma unroll
    for (int i = 0; i < NCELL/256; ++i) hist[i*256 + tid] = 0;
    __syncthreads();

    uint32_t rec[PXB/256];
    float px[PXB/256], py[PXB/256];
    const int p0 = blockIdx.x * PXB;
    #pragma unroll
    for (int i = 0; i < PXB/256; ++i) {
        const int p = p0 + i*256 + tid;
        const float x = grid_x[p], y = grid_y[p];
        px[i] = x; py[i] = y;
        int ix = (int)(x * 32.0f); ix = min(max(ix, 0), 31);
        int iy = (int)(y * 32.0f); iy = min(max(iy, 0), 31);
        const int cell = iy*32 + ix;
        const int lr = atomicAdd(&hist[cell], 1);       // LDS atomic: cheap
        rec[i] = ((uint32_t)cell << 11) | (uint32_t)lr; // lr < 1024 fits 11b
    }
    __syncthreads();
    #pragma unroll
    for (int i = 0; i < NCELL/256; ++i) {
        const int c = i*256 + tid;
        const int h = hist[c];
        base[c] = (h > 0) ? atomicAdd(&counts[c], h) : 0;  // spread over 1024 addrs
    }
    __syncthreads();
    #pragma unroll
    for (int i = 0; i < PXB/256; ++i) {
        const int p = p0 + i*256 + tid;
        const int cell = (int)(rec[i] >> 11);
        const int g = base[cell] + (int)(rec[i] & 0x7FFu);
        if (g < CAP) {
            bpx[cell*CAP + g] =
                make_float4(__int_as_float(p), px[i], py[i], 0.f);
        } else {
            const int t2 = atomicAdd(spilln, 1);
            if (t2 < SPILL_CAP) spill[t2] = p;
        }
    }
}

// ---------- kernel B: render, inline cull, 1 block/cell x 256 thr ----------
__global__ __launch_bounds__(256) void gabor_render(
    const float4* __restrict__ consts, const int* __restrict__ counts,
    const float4* __restrict__ bpx,
    const int* __restrict__ spill, const int* __restrict__ spilln,
    const float* __restrict__ grid_x, const float* __restrict__ grid_y,
    float* __restrict__ out)
{
    __shared__ float4 cs[4 * NG];
    __shared__ int s_wb[4];
    const int cell = blockIdx.x;
    const int tid = threadIdx.x;
    const float cxc = ((cell & 31) + 0.5f) * 0.03125f;
    const float cyc = ((cell >> 5) + 0.5f) * 0.03125f;

    // --- inline cull: 1 gabor/thread, order-preserving LDS compaction ---
    {
        const float4 A = consts[tid];
        const float4 B = consts[NG + tid];
        const float4 C = consts[2*NG + tid];
        const float4 D = consts[3*NG + tid];
        const float dx = cxc - A.x, dy = cyc - A.y;
        const float xrc = dx * A.z + dy * A.w;
        const float yrc = dy * A.z - dx * A.w;
        const float R = 0.0222f;            // cell half-diagonal + slack
        const float xl = fmaxf(fabsf(xrc) - R, 0.f);
        const float yl = fmaxf(fabsf(yrc) - R, 0.f);
        const float e2max = xl*xl*B.x + yl*yl*B.y;   // conservative bound
        const bool nz = (C.x != 0.f) | (C.y != 0.f) | (C.z != 0.f) |
                        (D.x != 0.f) | (D.y != 0.f) | (D.z != 0.f);
        const bool act = (e2max > -20.0f) && nz;
        const unsigned long long m = __ballot(act);
        const int lane = tid & 63, w = tid >> 6;
        if (lane == 0) s_wb[w] = __popcll(m);
        __syncthreads();
        int base = 0;
        #pragma unroll
        for (int i = 0; i < 4; ++i) base += (i < w) ? s_wb[i] : 0;
        if (act) {
            const int pos = base + __popcll(m & ((1ull << lane) - 1ull));
            cs[pos] = A; cs[NG+pos] = B; cs[2*NG+pos] = C; cs[3*NG+pos] = D;
        }
        __syncthreads();
    }
    const int ng = s_wb[0] + s_wb[1] + s_wb[2] + s_wb[3];

    // --- pixel loop: 1 px/thread, 64 same-cell px per wave ---
    const float c1f = 0.15915494309189535f;
    const float c2f = (float)(INV2PI_D - (double)0.15915494309189535f);
    const int cnt = min(counts[cell], CAP);
    const int sb = cell * CAP;
    for (int i = tid; i < cnt; i += 256) {
        const float4 pxk = bpx[sb + i];
        const int   p  = __float_as_int(pxk.x);
        const float gx = pxk.y, gy = pxk.z;
        float a0 = 0.f, a1 = 0.f, a2 = 0.f;
        #pragma unroll 2
        for (int j = 0; j < ng; ++j) {
            const float4 k0 = cs[j];
            const float4 k1 = cs[NG + j];
            const float dx = gx - k0.x;
            const float dy = gy - k0.y;
            float xr, yr;
            {
                // phase-critical: match np's separately-rounded mul/add
                #pragma clang fp contract(off)
                xr = dx * k0.z + dy * k0.w;
                yr = dy * k0.z - dx * k0.w;
            }
            const float e2 = fmaf(yr * yr, k1.y, xr * xr * k1.x);
            if (e2 > -20.0f) {
                const float g = __builtin_amdgcn_exp2f(e2);
                float fx;
                {
                    #pragma clang fp contract(off)
                    fx = k1.z * xr;          // phase-critical rounding
                }
                const float nn = __builtin_rintf(fx * c1f);
                float t = __builtin_fmaf(fx, c1f, -nn);
                t = __builtin_fmaf(fx, c2f, t);
                const float s = __builtin_amdgcn_sinf(t);
                const float c = __builtin_amdgcn_cosf(t);
                const float4 k2 = cs[2*NG + j];
                const float4 k3 = cs[3*NG + j];
                const float gc = g * c, gs = g * s;
                a0 = fmaf(gc, k2.x, fmaf(-gs, k3.x, a0));
                a1 = fmaf(gc, k2.y, fmaf(-gs, k3.y, a1));
                a2 = fmaf(gc, k2.z, fmaf(-gs, k3.z, a2));
            }
        }
        out[p]        = clampf(a0, -1.f, 1.f);
        out[HW + p]   = clampf(a1, -1.f, 1.f);
        out[2*HW + p] = clampf(a2, -1.f, 1.f);
    }

    // spill pixels (normally zero) handled by block 0 with full gabor list
    if (cell == 0) {
        const int sc = min(*spilln, SPILL_CAP);
        for (int i = tid; i < sc; i += 256) {
            const int p = spill[i];
            const float gx = grid_x[p], gy = grid_y[p];
            float a0 = 0.f, a1 = 0.f, a2 = 0.f;
            accum_list(consts, NG, gx, gy, a0, a1, a2);
            out[p]        = clampf(a0, -1.f, 1.f);
            out[HW + p]   = clampf(a1, -1.f, 1.f);
            out[2*HW + p] = clampf(a2, -1.f, 1.f);
        }
    }
}

// ---------- fallback paths (ws too small) ----------
__global__ __launch_bounds__(256) void gabor_consts_kernel(
    const float* __restrict__ u, const float* __restrict__ v,
    const float* __restrict__ theta, const float* __restrict__ rel_sigma,
    const float* __restrict__ rel_freq, const float* __restrict__ gamma,
    const float* __restrict__ psi, const float* __restrict__ amplitude,
    float4* __restrict__ ws)
{
    const int n = threadIdx.x;
    float4 A, B, C, D;
    compute_consts(n, u, v, theta, rel_sigma, rel_freq, gamma, psi, amplitude,
                   A, B, C, D);
    ws[n] = A; ws[NG + n] = B; ws[2*NG + n] = C; ws[3*NG + n] = D;
}

__global__ __launch_bounds__(256) void gabor_fwd_ws(
    const float4* __restrict__ ws,
    const float* __restrict__ grid_x, const float* __restrict__ grid_y,
    float* __restrict__ out)
{
    __shared__ float4 cs[4 * NG];
    const int tid = threadIdx.x;
    cs[tid]        = ws[tid];
    cs[tid + NG]   = ws[tid + NG];
    cs[tid + 2*NG] = ws[tid + 2*NG];
    cs[tid + 3*NG] = ws[tid + 3*NG];
    __syncthreads();
    const int p = blockIdx.x * 256 + tid;
    const float gx = grid_x[p], gy = grid_y[p];
    float a0 = 0.f, a1 = 0.f, a2 = 0.f;
    accum_list(cs, NG, gx, gy, a0, a1, a2);
    out[p]        = clampf(a0, -1.f, 1.f);
    out[HW + p]   = clampf(a1, -1.f, 1.f);
    out[2*HW + p] = clampf(a2, -1.f, 1.f);
}

__global__ __launch_bounds__(256) void gabor_fwd_fused(
    const float* __restrict__ grid_x, const float* __restrict__ grid_y,
    const float* __restrict__ u, const float* __restrict__ v,
    const float* __restrict__ theta, const float* __restrict__ rel_sigma,
    const float* __restrict__ rel_freq, const float* __restrict__ gamma,
    const float* __restrict__ psi, const float* __restrict__ amplitude,
    float* __restrict__ out)
{
    __shared__ float4 cs[4 * NG];
    const int tid = threadIdx.x;
    {
        float4 A, B, C, D;
        compute_consts(tid, u, v, theta, rel_sigma, rel_freq, gamma, psi,
                       amplitude, A, B, C, D);
        cs[tid] = A; cs[tid + NG] = B; cs[tid + 2*NG] = C; cs[tid + 3*NG] = D;
    }
    __syncthreads();
    const int p = blockIdx.x * 256 + tid;
    const float gx = grid_x[p], gy = grid_y[p];
    float a0 = 0.f, a1 = 0.f, a2 = 0.f;
    accum_list(cs, NG, gx, gy, a0, a1, a2);
    out[p]        = clampf(a0, -1.f, 1.f);
    out[HW + p]   = clampf(a1, -1.f, 1.f);
    out[2*HW + p] = clampf(a2, -1.f, 1.f);
}

extern "C" void kernel_launch(void* const* d_in, const int* in_sizes, int n_in,
                              void* d_out, int out_size, void* d_ws, size_t ws_size,
                              hipStream_t stream) {
    const float* grid_x    = (const float*)d_in[0];
    const float* grid_y    = (const float*)d_in[1];
    const float* u         = (const float*)d_in[2];
    const float* v         = (const float*)d_in[3];
    const float* theta     = (const float*)d_in[4];
    const float* rel_sigma = (const float*)d_in[5];
    const float* rel_freq  = (const float*)d_in[6];
    const float* gamma     = (const float*)d_in[7];
    const float* psi       = (const float*)d_in[8];
    const float* amplitude = (const float*)d_in[9];
    float* out = (float*)d_out;

    // ws layout (256B-aligned)
    const size_t OFF_CONSTS = 0;            // 16384
    const size_t OFF_COUNTS = 16384;        // 4096
    const size_t OFF_SPN    = 20480;        // 256
    const size_t OFF_SPILL  = 20736;        // 16384
    const size_t OFF_BPX    = 37120;        // 1024*384*16 = 6291456
    const size_t NEED       = 6328576;

    char* w = (char*)d_ws;

    if (ws_size >= NEED) {
        float4* consts = (float4*)(w + OFF_CONSTS);
        int*    counts = (int*)(w + OFF_COUNTS);
        int*    spn    = (int*)(w + OFF_SPN);
        int*    spill  = (int*)(w + OFF_SPILL);
        float4* bpx    = (float4*)(w + OFF_BPX);

        // zero counts + spilln (graph-capturable memset node)
        hipMemsetAsync(w + OFF_COUNTS, 0, 4096 + 256, stream);
        gabor_bin_consts<<<NBIN + 1, 256, 0, stream>>>(
            grid_x, grid_y, u, v, theta, rel_sigma, rel_freq, gamma,
            psi, amplitude, consts, counts, bpx, spill, spn);
        gabor_render<<<NCELL, 256, 0, stream>>>(
            consts, counts, bpx, spill, spn, grid_x, grid_y, out);
    } else if (ws_size >= 4u * NG * sizeof(float4)) {
        float4* ws = (float4*)d_ws;
        gabor_consts_kernel<<<1, NG, 0, stream>>>(
            u, v, theta, rel_sigma, rel_freq, gamma, psi, amplitude, ws);
        gabor_fwd_ws<<<HW / 256, 256, 0, stream>>>(ws, grid_x, grid_y, out);
    } else {
        gabor_fwd_fused<<<HW / 256, 256, 0, stream>>>(
            grid_x, grid_y, u, v, theta, rel_sigma, rel_freq, gamma,
            psi, amplitude, out);
    }
}

// Round 9
// 36.084 us; speedup vs baseline: 1.2878x; 1.0556x over previous
//
#include <hip/hip_runtime.h>
#include <stdint.h>

#define NG 256
#define HW (512*512)
#define NCELL 1024          // 32x32 cells
#define CAP 384             // bucket capacity per cell (Poisson(256), max ~330)
#define SPILL_CAP 4096
#define NBIN 256            // bin blocks
#define PXB (HW/NBIN)       // 1024 pixels per bin-block
#define TWO_PI_F 6.283185307179586f
#define L2E 1.4426950408889634f
#define INV2PI_D 0.15915494309189535

static __device__ __forceinline__ float clampf(float x, float lo, float hi) {
    return fminf(fmaxf(x, lo), hi);
}

// ---------- per-gabor constants (f64 -> correctly-rounded f32) ----------
static __device__ __forceinline__ void compute_consts(
    int n,
    const float* __restrict__ u, const float* __restrict__ v,
    const float* __restrict__ theta, const float* __restrict__ rel_sigma,
    const float* __restrict__ rel_freq, const float* __restrict__ gamma,
    const float* __restrict__ psi, const float* __restrict__ amplitude,
    float4& A, float4& B, float4& C, float4& D)
{
    const float uc = clampf(u[n], -1.f, 1.f);
    const float vc = clampf(v[n], -1.f, 1.f);
    const float th = clampf(theta[n], -2.f, 2.f) * TWO_PI_F;
    const float sg = clampf(rel_sigma[n], 1e-5f, 5.f);
    const float gm = clampf(gamma[n], 1e-5f, 5.f);
    const float cr = (float)::cos((double)th);
    const float sr = (float)::sin((double)th);
    const float i2s = 1.0f / (2.0f * sg * sg);
    const float i2g = 1.0f / (2.0f * gm * gm);
    const float E  = (float)::exp((double)rel_freq[n]);
    const float fq = TWO_PI_F / E;          // f32 division, mirrors np
    A = make_float4(uc, vc, cr, sr);
    B = make_float4(-(i2s * L2E), -(i2g * L2E), fq, 0.f);  // ready for exp2
    float ac[3], as[3];
    #pragma unroll
    for (int c = 0; c < 3; ++c) {
        const float ph = clampf(psi[n*3 + c], -1.f, 1.f) * TWO_PI_F;
        const float a  = clampf(amplitude[n*3 + c], 0.f, 1.f);
        ac[c] = a * (float)::cos((double)ph);
        as[c] = a * (float)::sin((double)ph);
    }
    C = make_float4(ac[0], ac[1], ac[2], 0.f);
    D = make_float4(as[0], as[1], as[2], 0.f);
}

// ---------- 1-pixel accumulate (spill + fallback paths) ----------
static __device__ __forceinline__ void accum_list(
    const float4* __restrict__ base, int ngab,
    float gx, float gy, float& a0, float& a1, float& a2)
{
    const float c1f = 0.15915494309189535f;
    const float c2f = (float)(INV2PI_D - (double)0.15915494309189535f);
    for (int j = 0; j < ngab; ++j) {
        const float4 k0 = base[j];
        const float4 k1 = base[NG + j];
        const float dx = gx - k0.x;
        const float dy = gy - k0.y;
        float xr, yr;
        {
            #pragma clang fp contract(off)
            xr = dx * k0.z + dy * k0.w;
            yr = dy * k0.z - dx * k0.w;
        }
        const float e2 = fmaf(yr * yr, k1.y, xr * xr * k1.x);
        if (e2 > -20.0f) {
            const float g = __builtin_amdgcn_exp2f(e2);
            float fx;
            {
                #pragma clang fp contract(off)
                fx = k1.z * xr;
            }
            const float nn = __builtin_rintf(fx * c1f);
            float t = __builtin_fmaf(fx, c1f, -nn);
            t = __builtin_fmaf(fx, c2f, t);
            const float s = __builtin_amdgcn_sinf(t);
            const float c = __builtin_amdgcn_cosf(t);
            const float4 k2 = base[2*NG + j];
            const float4 k3 = base[3*NG + j];
            const float gc = g * c, gs = g * s;
            a0 = fmaf(gc, k2.x, fmaf(-gs, k3.x, a0));
            a1 = fmaf(gc, k2.y, fmaf(-gs, k3.y, a1));
            a2 = fmaf(gc, k2.z, fmaf(-gs, k3.z, a2));
        }
    }
}

// ---------- kernel A: binning (blocks 0..255) + consts (block 256) ----------
__global__ __launch_bounds__(256) void gabor_bin_consts(
    const float* __restrict__ grid_x, const float* __restrict__ grid_y,
    const float* __restrict__ u, const float* __restrict__ v,
    const float* __restrict__ theta, const float* __restrict__ rel_sigma,
    const float* __restrict__ rel_freq, const float* __restrict__ gamma,
    const float* __restrict__ psi, const float* __restrict__ amplitude,
    float4* __restrict__ consts, int* __restrict__ counts,
    float4* __restrict__ bpx,
    int* __restrict__ spill, int* __restrict__ spilln)
{
    const int tid = threadIdx.x;
    if (blockIdx.x == NBIN) {  // consts block, runs concurrently with binning
        float4 A, B, C, D;
        compute_consts(tid, u, v, theta, rel_sigma, rel_freq, gamma, psi,
                       amplitude, A, B, C, D);
        consts[tid] = A; consts[NG+tid] = B;
        consts[2*NG+tid] = C; consts[3*NG+tid] = D;
        return;
    }
    __shared__ int hist[NCELL];
    __shared__ int base[NCELL];
    #pragma unroll
    for (int i = 0; i < NCELL/256; ++i) hist[i*256 + tid] = 0;
    __syncthreads();

    uint32_t rec[PXB/256];
    float px[PXB/256], py[PXB/256];
    const int p0 = blockIdx.x * PXB;
    #pragma unroll
    for (int i = 0; i < PXB/256; ++i) {
        const int p = p0 + i*256 + tid;
        const float x = grid_x[p], y = grid_y[p];
        px[i] = x; py[i] = y;
        int ix = (int)(x * 32.0f); ix = min(max(ix, 0), 31);
        int iy = (int)(y * 32.0f); iy = min(max(iy, 0), 31);
        const int cell = iy*32 + ix;
        const int lr = atomicAdd(&hist[cell], 1);       // LDS atomic: cheap
        rec[i] = ((uint32_t)cell << 11) | (uint32_t)lr; // lr < 1024 fits 11b
    }
    __syncthreads();
    #pragma unroll
    for (int i = 0; i < NCELL/256; ++i) {
        const int c = i*256 + tid;
        const int h = hist[c];
        base[c] = (h > 0) ? atomicAdd(&counts[c], h) : 0;  // 1024 addresses
    }
    __syncthreads();
    #pragma unroll
    for (int i = 0; i < PXB/256; ++i) {
        const int p = p0 + i*256 + tid;
        const int cell = (int)(rec[i] >> 11);
        const int g = base[cell] + (int)(rec[i] & 0x7FFu);
        if (g < CAP) {
            bpx[cell*CAP + g] =
                make_float4(__int_as_float(p), px[i], py[i], 0.f);
        } else {
            const int t2 = atomicAdd(spilln, 1);
            if (t2 < SPILL_CAP) spill[t2] = p;
        }
    }
}

// ---------- kernel B: render; cull splits G1 (hits whole cell, branchless)
// ---------- and G2 (edge, branchy). 1 block/cell x 256 thr.
__global__ __launch_bounds__(256) void gabor_render(
    const float4* __restrict__ consts, const int* __restrict__ counts,
    const float4* __restrict__ bpx,
    const int* __restrict__ spill, const int* __restrict__ spilln,
    const float* __restrict__ grid_x, const float* __restrict__ grid_y,
    float* __restrict__ out)
{
    __shared__ float4 cs[4 * NG];
    __shared__ int s_wb1[4], s_wb2[4];
    const int cell = blockIdx.x;
    const int tid = threadIdx.x;
    const float cxc = ((cell & 31) + 0.5f) * 0.03125f;
    const float cyc = ((cell >> 5) + 0.5f) * 0.03125f;

    // --- inline cull + G1/G2 segmented compaction ---
    {
        const float4 A = consts[tid];
        const float4 B = consts[NG + tid];
        const float4 C = consts[2*NG + tid];
        const float4 D = consts[3*NG + tid];
        const float dx = cxc - A.x, dy = cyc - A.y;
        const float xrc = dx * A.z + dy * A.w;
        const float yrc = dy * A.z - dx * A.w;
        const float R = 0.0222f;            // cell half-diagonal + slack
        const float axr = fabsf(xrc), ayr = fabsf(yrc);
        const float xl = fmaxf(axr - R, 0.f), yl = fmaxf(ayr - R, 0.f);
        const float xh = axr + R,            yh = ayr + R;
        // B.x,B.y <= 0: e2 over the cell lies in [e2min, e2max]
        const float e2max = xl*xl*B.x + yl*yl*B.y;
        const float e2min = xh*xh*B.x + yh*yh*B.y;
        const bool nz = (C.x != 0.f) | (C.y != 0.f) | (C.z != 0.f) |
                        (D.x != 0.f) | (D.y != 0.f) | (D.z != 0.f);
        const bool act = (e2max > -20.0f) && nz;
        const bool g1  = act && (e2min > -20.0f);   // hits EVERY px in cell
        const bool g2  = act && !g1;                // edge gabor
        const unsigned long long m1 = __ballot(g1);
        const unsigned long long m2 = __ballot(g2);
        const int lane = tid & 63, w = tid >> 6;
        if (lane == 0) { s_wb1[w] = __popcll(m1); s_wb2[w] = __popcll(m2); }
        __syncthreads();
        const int n1 = s_wb1[0] + s_wb1[1] + s_wb1[2] + s_wb1[3];
        int b1 = 0, b2 = n1;
        #pragma unroll
        for (int i = 0; i < 4; ++i) {
            b1 += (i < w) ? s_wb1[i] : 0;
            b2 += (i < w) ? s_wb2[i] : 0;
        }
        const unsigned long long lm = (1ull << lane) - 1ull;
        if (g1) {
            const int pos = b1 + __popcll(m1 & lm);
            cs[pos] = A; cs[NG+pos] = B; cs[2*NG+pos] = C; cs[3*NG+pos] = D;
        }
        if (g2) {
            const int pos = b2 + __popcll(m2 & lm);
            cs[pos] = A; cs[NG+pos] = B; cs[2*NG+pos] = C; cs[3*NG+pos] = D;
        }
        __syncthreads();
    }
    const int n1 = s_wb1[0] + s_wb1[1] + s_wb1[2] + s_wb1[3];
    const int ng = n1 + s_wb2[0] + s_wb2[1] + s_wb2[2] + s_wb2[3];

    // --- pixel loop: 1 px/thread, 64 same-cell px per wave ---
    const float c1f = 0.15915494309189535f;
    const float c2f = (float)(INV2PI_D - (double)0.15915494309189535f);
    const int cnt = min(counts[cell], CAP);
    const int sb = cell * CAP;
    for (int i = tid; i < cnt; i += 256) {
        const float4 pxk = bpx[sb + i];
        const int   p  = __float_as_int(pxk.x);
        const float gx = pxk.y, gy = pxk.z;
        float a0 = 0.f, a1 = 0.f, a2 = 0.f;
        // G1: branchless, unroll 2 -> two independent dep chains
        #pragma unroll 2
        for (int j = 0; j < n1; ++j) {
            const float4 k0 = cs[j];
            const float4 k1 = cs[NG + j];
            const float dx = gx - k0.x;
            const float dy = gy - k0.y;
            float xr, yr;
            {
                // phase-critical: match np's separately-rounded mul/add
                #pragma clang fp contract(off)
                xr = dx * k0.z + dy * k0.w;
                yr = dy * k0.z - dx * k0.w;
            }
            const float e2 = fmaf(yr * yr, k1.y, xr * xr * k1.x);
            const float g = __builtin_amdgcn_exp2f(e2);
            float fx;
            {
                #pragma clang fp contract(off)
                fx = k1.z * xr;              // phase-critical rounding
            }
            const float nn = __builtin_rintf(fx * c1f);
            float t = __builtin_fmaf(fx, c1f, -nn);
            t = __builtin_fmaf(fx, c2f, t);
            const float s = __builtin_amdgcn_sinf(t);
            const float c = __builtin_amdgcn_cosf(t);
            const float4 k2 = cs[2*NG + j];
            const float4 k3 = cs[3*NG + j];
            const float gc = g * c, gs = g * s;
            a0 = fmaf(gc, k2.x, fmaf(-gs, k3.x, a0));
            a1 = fmaf(gc, k2.y, fmaf(-gs, k3.y, a1));
            a2 = fmaf(gc, k2.z, fmaf(-gs, k3.z, a2));
        }
        // G2: edge gabors, keep the skip branch
        for (int j = n1; j < ng; ++j) {
            const float4 k0 = cs[j];
            const float4 k1 = cs[NG + j];
            const float dx = gx - k0.x;
            const float dy = gy - k0.y;
            float xr, yr;
            {
                #pragma clang fp contract(off)
                xr = dx * k0.z + dy * k0.w;
                yr = dy * k0.z - dx * k0.w;
            }
            const float e2 = fmaf(yr * yr, k1.y, xr * xr * k1.x);
            if (e2 > -20.0f) {
                const float g = __builtin_amdgcn_exp2f(e2);
                float fx;
                {
                    #pragma clang fp contract(off)
                    fx = k1.z * xr;
                }
                const float nn = __builtin_rintf(fx * c1f);
                float t = __builtin_fmaf(fx, c1f, -nn);
                t = __builtin_fmaf(fx, c2f, t);
                const float s = __builtin_amdgcn_sinf(t);
                const float c = __builtin_amdgcn_cosf(t);
                const float4 k2 = cs[2*NG + j];
                const float4 k3 = cs[3*NG + j];
                const float gc = g * c, gs = g * s;
                a0 = fmaf(gc, k2.x, fmaf(-gs, k3.x, a0));
                a1 = fmaf(gc, k2.y, fmaf(-gs, k3.y, a1));
                a2 = fmaf(gc, k2.z, fmaf(-gs, k3.z, a2));
            }
        }
        out[p]        = clampf(a0, -1.f, 1.f);
        out[HW + p]   = clampf(a1, -1.f, 1.f);
        out[2*HW + p] = clampf(a2, -1.f, 1.f);
    }

    // spill pixels (normally zero) handled by block 0 with full gabor list
    if (cell == 0) {
        const int sc = min(*spilln, SPILL_CAP);
        for (int i = tid; i < sc; i += 256) {
            const int p = spill[i];
            const float gx = grid_x[p], gy = grid_y[p];
            float a0 = 0.f, a1 = 0.f, a2 = 0.f;
            accum_list(consts, NG, gx, gy, a0, a1, a2);
            out[p]        = clampf(a0, -1.f, 1.f);
            out[HW + p]   = clampf(a1, -1.f, 1.f);
            out[2*HW + p] = clampf(a2, -1.f, 1.f);
        }
    }
}

// ---------- fallback paths (ws too small) ----------
__global__ __launch_bounds__(256) void gabor_consts_kernel(
    const float* __restrict__ u, const float* __restrict__ v,
    const float* __restrict__ theta, const float* __restrict__ rel_sigma,
    const float* __restrict__ rel_freq, const float* __restrict__ gamma,
    const float* __restrict__ psi, const float* __restrict__ amplitude,
    float4* __restrict__ ws)
{
    const int n = threadIdx.x;
    float4 A, B, C, D;
    compute_consts(n, u, v, theta, rel_sigma, rel_freq, gamma, psi, amplitude,
                   A, B, C, D);
    ws[n] = A; ws[NG + n] = B; ws[2*NG + n] = C; ws[3*NG + n] = D;
}

__global__ __launch_bounds__(256) void gabor_fwd_ws(
    const float4* __restrict__ ws,
    const float* __restrict__ grid_x, const float* __restrict__ grid_y,
    float* __restrict__ out)
{
    __shared__ float4 cs[4 * NG];
    const int tid = threadIdx.x;
    cs[tid]        = ws[tid];
    cs[tid + NG]   = ws[tid + NG];
    cs[tid + 2*NG] = ws[tid + 2*NG];
    cs[tid + 3*NG] = ws[tid + 3*NG];
    __syncthreads();
    const int p = blockIdx.x * 256 + tid;
    const float gx = grid_x[p], gy = grid_y[p];
    float a0 = 0.f, a1 = 0.f, a2 = 0.f;
    accum_list(cs, NG, gx, gy, a0, a1, a2);
    out[p]        = clampf(a0, -1.f, 1.f);
    out[HW + p]   = clampf(a1, -1.f, 1.f);
    out[2*HW + p] = clampf(a2, -1.f, 1.f);
}

__global__ __launch_bounds__(256) void gabor_fwd_fused(
    const float* __restrict__ grid_x, const float* __restrict__ grid_y,
    const float* __restrict__ u, const float* __restrict__ v,
    const float* __restrict__ theta, const float* __restrict__ rel_sigma,
    const float* __restrict__ rel_freq, const float* __restrict__ gamma,
    const float* __restrict__ psi, const float* __restrict__ amplitude,
    float* __restrict__ out)
{
    __shared__ float4 cs[4 * NG];
    const int tid = threadIdx.x;
    {
        float4 A, B, C, D;
        compute_consts(tid, u, v, theta, rel_sigma, rel_freq, gamma, psi,
                       amplitude, A, B, C, D);
        cs[tid] = A; cs[tid + NG] = B; cs[tid + 2*NG] = C; cs[tid + 3*NG] = D;
    }
    __syncthreads();
    const int p = blockIdx.x * 256 + tid;
    const float gx = grid_x[p], gy = grid_y[p];
    float a0 = 0.f, a1 = 0.f, a2 = 0.f;
    accum_list(cs, NG, gx, gy, a0, a1, a2);
    out[p]        = clampf(a0, -1.f, 1.f);
    out[HW + p]   = clampf(a1, -1.f, 1.f);
    out[2*HW + p] = clampf(a2, -1.f, 1.f);
}

extern "C" void kernel_launch(void* const* d_in, const int* in_sizes, int n_in,
                              void* d_out, int out_size, void* d_ws, size_t ws_size,
                              hipStream_t stream) {
    const float* grid_x    = (const float*)d_in[0];
    const float* grid_y    = (const float*)d_in[1];
    const float* u         = (const float*)d_in[2];
    const float* v         = (const float*)d_in[3];
    const float* theta     = (const float*)d_in[4];
    const float* rel_sigma = (const float*)d_in[5];
    const float* rel_freq  = (const float*)d_in[6];
    const float* gamma     = (const float*)d_in[7];
    const float* psi       = (const float*)d_in[8];
    const float* amplitude = (const float*)d_in[9];
    float* out = (float*)d_out;

    // ws layout (256B-aligned)
    const size_t OFF_CONSTS = 0;            // 16384
    const size_t OFF_COUNTS = 16384;        // 4096
    const size_t OFF_SPN    = 20480;        // 256
    const size_t OFF_SPILL  = 20736;        // 16384
    const size_t OFF_BPX    = 37120;        // 1024*384*16 = 6291456
    const size_t NEED       = 6328576;

    char* w = (char*)d_ws;

    if (ws_size >= NEED) {
        float4* consts = (float4*)(w + OFF_CONSTS);
        int*    counts = (int*)(w + OFF_COUNTS);
        int*    spn    = (int*)(w + OFF_SPN);
        int*    spill  = (int*)(w + OFF_SPILL);
        float4* bpx    = (float4*)(w + OFF_BPX);

        // zero counts + spilln (graph-capturable memset node)
        hipMemsetAsync(w + OFF_COUNTS, 0, 4096 + 256, stream);
        gabor_bin_consts<<<NBIN + 1, 256, 0, stream>>>(
            grid_x, grid_y, u, v, theta, rel_sigma, rel_freq, gamma,
            psi, amplitude, consts, counts, bpx, spill, spn);
        gabor_render<<<NCELL, 256, 0, stream>>>(
            consts, counts, bpx, spill, spn, grid_x, grid_y, out);
    } else if (ws_size >= 4u * NG * sizeof(float4)) {
        float4* ws = (float4*)d_ws;
        gabor_consts_kernel<<<1, NG, 0, stream>>>(
            u, v, theta, rel_sigma, rel_freq, gamma, psi, amplitude, ws);
        gabor_fwd_ws<<<HW / 256, 256, 0, stream>>>(ws, grid_x, grid_y, out);
    } else {
        gabor_fwd_fused<<<HW / 256, 256, 0, stream>>>(
            grid_x, grid_y, u, v, theta, rel_sigma, rel_freq, gamma,
            psi, amplitude, out);
    }
}